// Round 13
// baseline (458.810 us; speedup 1.0000x reference)
//
#include <hip/hip_runtime.h>
#include <hip/hip_fp16.h>
#include <cmath>

#define NLEV 16
#define HASH_START 12               // levels >= 12 use spatial hash ((r+1)^2 > 2^19)
#define HMASK ((1u << 19) - 1u)     // hash level size is exactly 2^19
#define HASH_PRIME 2654435761u
#define LDS_WORDS 14160             // offset[6]: entries of levels 0-5 (host-guarded)

typedef float    f4 __attribute__((ext_vector_type(4)));
typedef unsigned u4 __attribute__((ext_vector_type(4)));

struct LvlC {
  float scale[NLEV];
  unsigned stride[NLEV];   // res + 1
  unsigned offset[NLEV];   // offsets in ORIGINAL fp32 per-plane table
  unsigned dupoff[NLEV];   // levels 6-11: offsets of row-pair dup tables in tab16
};

__device__ __forceinline__ float2 h2f(unsigned u) {
  return __half22float2(__builtin_bit_cast(__half2, u));
}

// ---- convert levels 0-5 -> fp16 at tab16[0..LDS_WORDS) per plane ----
__global__ __launch_bounds__(256) void k_convert05(
    const float2* __restrict__ t0, const float2* __restrict__ t1,
    const float2* __restrict__ t2, unsigned* __restrict__ dst, unsigned total16)
{
  unsigned idx = blockIdx.x * 256 + threadIdx.x;
  if (idx >= 3u * LDS_WORDS) return;
  unsigned p = idx / LDS_WORDS, e = idx % LDS_WORDS;
  const float2* src = (p == 0) ? t0 : ((p == 1) ? t1 : t2);
  float2 v = src[e];
  dst[(size_t)p * total16 + e] =
      __builtin_bit_cast(unsigned, __floats2half2_rn(v.x, v.y));
}

// ---- build row-pair dup table for one dense level:
//      dup[(y*st+x)*2] = {fp16(t[y][x]), fp16(t[y+1][x])} ----
__global__ __launch_bounds__(256) void k_convert_dup(
    const float2* __restrict__ t0, const float2* __restrict__ t1,
    const float2* __restrict__ t2, unsigned* __restrict__ dst,
    unsigned src_off, unsigned dst_off, unsigned st, unsigned total16)
{
  unsigned x = blockIdx.x * 256 + threadIdx.x;
  if (x >= st) return;
  unsigned y = blockIdx.y;
  unsigned p = blockIdx.z;
  const float2* src = (p == 0) ? t0 : ((p == 1) ? t1 : t2);
  float2 a = src[src_off + (size_t)y * st + x];
  float2 b = src[src_off + (size_t)(y + 1) * st + x];
  uint2 w;
  w.x = __builtin_bit_cast(unsigned, __floats2half2_rn(a.x, a.y));
  w.y = __builtin_bit_cast(unsigned, __floats2half2_rn(b.x, b.y));
  *reinterpret_cast<uint2*>(dst + (size_t)p * total16 + dst_off +
                            (size_t)(y * st + x) * 2) = w;
}

// even-x0 trick on fp32 hash table: pair {a0, a0^1} is one aligned float4
__device__ __forceinline__ void hash_row_f32(
    const float2* __restrict__ tp, unsigned x0, unsigned hy,
    float2& g0, float2& g1)
{
  unsigned a0 = (x0 ^ hy) & HMASK;
  if ((x0 & 1u) == 0u) {
    f4 v = *reinterpret_cast<const f4*>(tp + (a0 & ~1u));  // 16B-aligned
    bool hi = (a0 & 1u) != 0u;
    g0 = hi ? make_float2(v.z, v.w) : make_float2(v.x, v.y);
    g1 = hi ? make_float2(v.x, v.y) : make_float2(v.z, v.w);
  } else {
    g0 = tp[a0];
    g1 = tp[((x0 + 1u) ^ hy) & HMASK];
  }
}

// ---- fused gather: dense 6-11 via dup tables (1 req/level-plane) +
//      hash 12-15 from original fp32 tables -> 10 slices ----
__global__ __launch_bounds__(256) void k_gather(
    const float* __restrict__ pts, const unsigned* __restrict__ tab16,
    const float2* __restrict__ t0, const float2* __restrict__ t1,
    const float2* __restrict__ t2,
    unsigned* __restrict__ slices, LvlC lc, unsigned total16, int n)
{
  int i = blockIdx.x * 256 + threadIdx.x;
  if (i >= n) return;
  float u0 = (pts[3 * i + 0] + 1.f) * .5f;
  float u1 = (pts[3 * i + 1] + 1.f) * .5f;
  float u2 = (pts[3 * i + 2] + 1.f) * .5f;
  const float ua[3] = {u0, u0, u1}, ub[3] = {u1, u2, u2};   // COO_COMBS
  const float2* tabs[3] = {t0, t1, t2};

  // dense levels 6-11: three sequential 2-level groups
#pragma unroll 1
  for (int grp = 0; grp < 3; ++grp) {
    const int l0 = 6 + 2 * grp;
    u4 g[2][3];
    float gx[2][3], gy[2][3];
#pragma unroll
    for (int h = 0; h < 2; ++h) {
      const float sc = lc.scale[l0 + h];
      const unsigned st = lc.stride[l0 + h], o = lc.dupoff[l0 + h];
#pragma unroll
      for (int p = 0; p < 3; ++p) {
        float px = ua[p] * sc + .5f, py = ub[p] * sc + .5f;
        float fx = floorf(px), fy = floorf(py);
        gx[h][p] = px - fx; gy[h][p] = py - fy;
        unsigned e = ((unsigned)fy * st + (unsigned)fx) * 2 + o;
        g[h][p] = *reinterpret_cast<const u4*>(tab16 + (size_t)p * total16 + e);
        // g = {t[y0][x0], t[y0+1][x0], t[y0][x0+1], t[y0+1][x0+1]} as fp16x2
      }
    }
#pragma unroll
    for (int h = 0; h < 2; ++h) {
      float s0 = 0.f, s1 = 0.f;
#pragma unroll
      for (int p = 0; p < 3; ++p) {
        float x = gx[h][p], y = gy[h][p];
        float w00 = (1.f - x) * (1.f - y), w01 = (1.f - x) * y;
        float w10 = x * (1.f - y),          w11 = x * y;
        float2 f00 = h2f(g[h][p].x), f01 = h2f(g[h][p].y);
        float2 f10 = h2f(g[h][p].z), f11 = h2f(g[h][p].w);
        s0 += w00 * f00.x + w10 * f10.x + w01 * f01.x + w11 * f11.x;
        s1 += w00 * f00.y + w10 * f10.y + w01 * f01.y + w11 * f11.y;
      }
      __builtin_nontemporal_store(
          __builtin_bit_cast(unsigned, __floats2half2_rn(s0, s1)),
          slices + (size_t)(2 * grp + h) * n + i);
    }
  }

  // hash levels 12-15: two sequential 2-level groups, fp32 tables
#pragma unroll 1
  for (int grp = 0; grp < 2; ++grp) {
    const int l0 = HASH_START + 2 * grp;
    float2 g[2][3][4];
    float rx[2][3], ry[2][3];
#pragma unroll
    for (int h = 0; h < 2; ++h) {
      const float sc = lc.scale[l0 + h];
      const unsigned o = lc.offset[l0 + h];
#pragma unroll
      for (int p = 0; p < 3; ++p) {
        float px = ua[p] * sc + .5f, py = ub[p] * sc + .5f;
        float fx = floorf(px), fy = floorf(py);
        rx[h][p] = px - fx; ry[h][p] = py - fy;
        unsigned x0 = (unsigned)fx, y0 = (unsigned)fy;
        unsigned hy0 = y0 * HASH_PRIME, hy1 = hy0 + HASH_PRIME;
        const float2* tp = tabs[p] + o;
        hash_row_f32(tp, x0, hy0, g[h][p][0], g[h][p][1]);
        hash_row_f32(tp, x0, hy1, g[h][p][2], g[h][p][3]);
      }
    }
#pragma unroll
    for (int h = 0; h < 2; ++h) {
      float s0 = 0.f, s1 = 0.f;
#pragma unroll
      for (int p = 0; p < 3; ++p) {
        float x = rx[h][p], y = ry[h][p];
        float w00 = (1.f - x) * (1.f - y), w10 = x * (1.f - y);
        float w01 = (1.f - x) * y,          w11 = x * y;
        s0 += w00 * g[h][p][0].x + w10 * g[h][p][1].x +
              w01 * g[h][p][2].x + w11 * g[h][p][3].x;
        s1 += w00 * g[h][p][0].y + w10 * g[h][p][1].y +
              w01 * g[h][p][2].y + w11 * g[h][p][3].y;
      }
      __builtin_nontemporal_store(
          __builtin_bit_cast(unsigned, __floats2half2_rn(s0, s1)),
          slices + (size_t)(6 + 2 * grp + h) * n + i);
    }
  }
}

// ---- final: persistent blocks (512 x 512thr, 4 pts/thread) -> staging of
//      levels 0-5 read once per block (87MB total vs 348MB) + slice merge ----
__global__ __launch_bounds__(512) void k_final(
    const float* __restrict__ pts, const unsigned* __restrict__ tab16,
    const unsigned* __restrict__ slices,   // 10 x n, levels 6..15
    float* __restrict__ out, LvlC lc, unsigned total16, int n)
{
  __shared__ unsigned lds[LDS_WORDS];
  const int tid = threadIdx.x;
  const int base = blockIdx.x * 2048;      // 4 pts/thread: 2 chunks x 2 halves

  int idx[2][2];
#pragma unroll
  for (int c = 0; c < 2; ++c)
#pragma unroll
    for (int k = 0; k < 2; ++k) idx[c][k] = base + c * 1024 + k * 512 + tid;

  float ua[2][2][3], ub[2][2][3];
#pragma unroll
  for (int c = 0; c < 2; ++c)
#pragma unroll
    for (int k = 0; k < 2; ++k) {
      float v0 = (pts[3 * idx[c][k] + 0] + 1.f) * .5f;
      float v1 = (pts[3 * idx[c][k] + 1] + 1.f) * .5f;
      float v2 = (pts[3 * idx[c][k] + 2] + 1.f) * .5f;
      ua[c][k][0] = v0; ub[c][k][0] = v1;
      ua[c][k][1] = v0; ub[c][k][1] = v2;
      ua[c][k][2] = v1; ub[c][k][2] = v2;
    }

  float res[2][2][12];
#pragma unroll
  for (int c = 0; c < 2; ++c)
#pragma unroll
    for (int k = 0; k < 2; ++k)
#pragma unroll
      for (int j = 0; j < 12; ++j) res[c][k][j] = 0.f;

  for (int p = 0; p < 3; ++p) {
    if (p) __syncthreads();
    const u4* src = reinterpret_cast<const u4*>(tab16 + (size_t)p * total16);
    for (unsigned e = tid; e < LDS_WORDS / 4; e += 512)
      reinterpret_cast<u4*>(lds)[e] = src[e];
    __syncthreads();
#pragma unroll
    for (int l = 0; l < 6; ++l) {
      const float sc = lc.scale[l];
      const unsigned st = lc.stride[l], o = lc.offset[l];
#pragma unroll
      for (int c = 0; c < 2; ++c)
#pragma unroll
        for (int k = 0; k < 2; ++k) {
          float px = ua[c][k][p] * sc + .5f, py = ub[c][k][p] * sc + .5f;
          float fx = floorf(px), fy = floorf(py);
          float x = px - fx, y = py - fy;
          unsigned i00 = (unsigned)fx + (unsigned)fy * st + o;
          float2 f00 = h2f(lds[i00]),      f10 = h2f(lds[i00 + 1]);
          float2 f01 = h2f(lds[i00 + st]), f11 = h2f(lds[i00 + st + 1]);
          float w00 = (1.f - x) * (1.f - y), w10 = x * (1.f - y);
          float w01 = (1.f - x) * y,          w11 = x * y;
          res[c][k][2 * l + 0] += w00 * f00.x + w10 * f10.x + w01 * f01.x + w11 * f11.x;
          res[c][k][2 * l + 1] += w00 * f00.y + w10 * f10.y + w01 * f01.y + w11 * f11.y;
        }
    }
  }

#pragma unroll
  for (int c = 0; c < 2; ++c)
#pragma unroll
    for (int k = 0; k < 2; ++k) {
      unsigned sl[10];
#pragma unroll
      for (int j = 0; j < 10; ++j) sl[j] = slices[(size_t)j * n + idx[c][k]];
      float v[32];
#pragma unroll
      for (int j = 0; j < 12; ++j) v[j] = res[c][k][j];
#pragma unroll
      for (int j = 0; j < 10; ++j) {
        float2 f = h2f(sl[j]);
        v[12 + 2 * j] = f.x; v[12 + 2 * j + 1] = f.y;
      }
      float4* o4 = (float4*)(out + (size_t)idx[c][k] * 32);
#pragma unroll
      for (int j = 0; j < 8; ++j)
        o4[j] = make_float4(v[4 * j], v[4 * j + 1], v[4 * j + 2], v[4 * j + 3]);
    }
}

// ---- fallback: monolithic fp32 (guards failed) ----
__global__ __launch_bounds__(256) void k_fallback(
    const float* __restrict__ pts, const float2* __restrict__ txy,
    const float2* __restrict__ txz, const float2* __restrict__ tyz,
    float* __restrict__ out, LvlC lc, int n)
{
  int i = blockIdx.x * 256 + threadIdx.x;
  if (i >= n) return;
  float u0 = (pts[3 * i + 0] + 1.f) * .5f;
  float u1 = (pts[3 * i + 1] + 1.f) * .5f;
  float u2 = (pts[3 * i + 2] + 1.f) * .5f;
  const float ua[3] = {u0, u0, u1}, ub[3] = {u1, u2, u2};
  const float2* tabs[3] = {txy, txz, tyz};
  float acc[32];
#pragma unroll
  for (int j = 0; j < 32; ++j) acc[j] = 0.f;
#pragma unroll
  for (int l = 0; l < NLEV; ++l) {
    const float sc = lc.scale[l];
    const unsigned o = lc.offset[l], s = lc.stride[l];
#pragma unroll
    for (int p = 0; p < 3; ++p) {
      const float2* t = tabs[p];
      float px = ua[p] * sc + .5f, py = ub[p] * sc + .5f;
      float fx = floorf(px), fy = floorf(py);
      float rx = px - fx, ry = py - fy;
      unsigned x0 = (unsigned)fx, y0 = (unsigned)fy;
      float w00 = (1.f - rx) * (1.f - ry), w10 = rx * (1.f - ry);
      float w01 = (1.f - rx) * ry,          w11 = rx * ry;
      float2 f00, f10, f01, f11;
      if (l >= HASH_START) {
        unsigned hy0 = y0 * HASH_PRIME, hy1 = hy0 + HASH_PRIME;
        f00 = t[o + ((x0 ^ hy0) & HMASK)];
        f10 = t[o + (((x0 + 1u) ^ hy0) & HMASK)];
        f01 = t[o + ((x0 ^ hy1) & HMASK)];
        f11 = t[o + (((x0 + 1u) ^ hy1) & HMASK)];
      } else {
        unsigned i00 = x0 + y0 * s;
        float4 r0 = *reinterpret_cast<const float4*>(t + o + i00);
        float4 r1 = *reinterpret_cast<const float4*>(t + o + i00 + s);
        f00 = make_float2(r0.x, r0.y); f10 = make_float2(r0.z, r0.w);
        f01 = make_float2(r1.x, r1.y); f11 = make_float2(r1.z, r1.w);
      }
      acc[2 * l + 0] += w00 * f00.x + w10 * f10.x + w01 * f01.x + w11 * f11.x;
      acc[2 * l + 1] += w00 * f00.y + w10 * f10.y + w01 * f01.y + w11 * f11.y;
    }
  }
  float4* o4 = (float4*)(out + (size_t)i * 32);
#pragma unroll
  for (int j = 0; j < 8; ++j)
    o4[j] = make_float4(acc[4 * j], acc[4 * j + 1], acc[4 * j + 2], acc[4 * j + 3]);
}

static unsigned compute_levels(LvlC* lc, unsigned* total16_out)
{
  // Mirrors Python _level_constants() with identical double-precision ops.
  const double pls = std::pow(2.0, std::log2(2048.0 / 16.0) / 15.0);
  unsigned long long off = 0;
  unsigned sizes[NLEV];
  for (int l = 0; l < NLEV; ++l) {
    double s = 16.0 * std::pow(pls, (double)l) - 1.0;
    lc->scale[l] = (float)s;
    long long r = (long long)std::ceil(s) + 1;
    long long dense = (r + 1) * (r + 1);
    long long sz = dense < (1LL << 19) ? dense : (1LL << 19);
    sz = ((sz + 7) / 8) * 8;
    lc->stride[l] = (unsigned)(r + 1);
    lc->offset[l] = (unsigned)off;
    sizes[l] = (unsigned)sz;
    lc->dupoff[l] = 0;
    off += (unsigned long long)sz;
  }
  // tab16 layout: [0, LDS_WORDS) = levels 0-5 fp16; then dup tables 6-11
  unsigned d = lc->offset[6];
  for (int l = 6; l < 12; ++l) {
    lc->dupoff[l] = d;
    d += 2u * lc->stride[l] * (lc->stride[l] - 1);
  }
  *total16_out = d;
  return (unsigned)off;
}

extern "C" void kernel_launch(void* const* d_in, const int* in_sizes, int n_in,
                              void* d_out, int out_size, void* d_ws, size_t ws_size,
                              hipStream_t stream) {
  const float*  pts = (const float*)d_in[0];
  const float2* txy = (const float2*)d_in[1];
  const float2* txz = (const float2*)d_in[2];
  const float2* tyz = (const float2*)d_in[3];
  float* out = (float*)d_out;
  int n = in_sizes[0] / 3;  // 1048576 points

  LvlC lc;
  unsigned total16;
  unsigned total = compute_levels(&lc, &total16);

  size_t tab_bytes = (size_t)3 * total16 * 4;
  size_t tab_al = (tab_bytes + 255) & ~(size_t)255;
  size_t need = tab_al + (size_t)10 * n * 4;

  bool ok = (n % 2048 == 0) && (lc.offset[6] == LDS_WORDS) && (ws_size >= need);
  for (int l = HASH_START; l < NLEV; ++l) {
    unsigned sz = ((l + 1 < NLEV) ? lc.offset[l + 1] : total) - lc.offset[l];
    ok = ok && (sz == (1u << 19));
  }

  int block = 256;
  int grid = (n + block - 1) / block;
  if (!ok) {
    k_fallback<<<grid, block, 0, stream>>>(pts, txy, txz, tyz, out, lc, n);
    return;
  }

  unsigned* tab16 = (unsigned*)d_ws;
  unsigned* slices = (unsigned*)((char*)d_ws + tab_al);  // 10 x n (levels 6..15)

  k_convert05<<<(3 * LDS_WORDS + 255) / 256, 256, 0, stream>>>(
      txy, txz, tyz, tab16, total16);
  for (int l = 6; l < 12; ++l) {
    unsigned st = lc.stride[l];
    dim3 g((st + 255) / 256, st - 1, 3);
    k_convert_dup<<<g, 256, 0, stream>>>(txy, txz, tyz, tab16,
                                         lc.offset[l], lc.dupoff[l], st, total16);
  }
  k_gather<<<grid, block, 0, stream>>>(pts, tab16, txy, txz, tyz,
                                       slices, lc, total16, n);
  k_final<<<n / 2048, 512, 0, stream>>>(pts, tab16, slices, out, lc, total16, n);
}

// Round 14
// 357.314 us; speedup vs baseline: 1.2841x; 1.2841x over previous
//
#include <hip/hip_runtime.h>
#include <hip/hip_fp16.h>
#include <cmath>

#define NLEV 16
#define HASH_START 12               // levels >= 12 use spatial hash ((r+1)^2 > 2^19)
#define HMASK ((1u << 19) - 1u)     // hash level size is exactly 2^19
#define HASH_PRIME 2654435761u
#define LDS_WORDS 14160             // offset[6]: entries of levels 0-5 (host-guarded)

typedef float    f4 __attribute__((ext_vector_type(4)));
typedef unsigned u4 __attribute__((ext_vector_type(4)));

struct LvlC {
  float scale[NLEV];
  unsigned stride[NLEV];   // res + 1
  unsigned offset[NLEV];   // cumulative param offset (multiple of 8)
};

__device__ __forceinline__ float2 h2f(unsigned u) {
  return __half22float2(__builtin_bit_cast(__half2, u));
}

// ---- pass 0: fp32 tables -> fp16 copies in ws ----
__global__ __launch_bounds__(256) void k_convert(
    const float2* __restrict__ t0, const float2* __restrict__ t1,
    const float2* __restrict__ t2, unsigned* __restrict__ dst, unsigned total)
{
  unsigned g = blockIdx.x * 256 + threadIdx.x;
  unsigned stp = gridDim.x * 256;
  unsigned tot3 = 3u * total;
  for (unsigned e = g; e < tot3; e += stp) {
    const float2* src; unsigned i = e;
    if (i < total)            { src = t0; }
    else if (i < 2u * total)  { src = t1; i -= total; }
    else                      { src = t2; i -= 2u * total; }
    float2 v = src[i];
    __half2 h = __floats2half2_rn(v.x, v.y);
    __builtin_nontemporal_store(__builtin_bit_cast(unsigned, h), dst + e);
  }
}

// ---- generic dense 2-level pair: 2 pts/thread, 24 uint2 gathers in flight ----
__global__ __launch_bounds__(256) void k_dense_pair(
    const float* __restrict__ pts, const unsigned* __restrict__ tab,
    unsigned* __restrict__ sA, unsigned* __restrict__ sB,
    float scA, unsigned stA, unsigned oA,
    float scB, unsigned stB, unsigned oB,
    unsigned total, int half)
{
  int t = blockIdx.x * 256 + threadIdx.x;
  if (t >= half) return;
  const int idx[2] = {t, t + half};

  float ua[2][3], ub[2][3];
#pragma unroll
  for (int k = 0; k < 2; ++k) {
    float u0 = (pts[3 * idx[k] + 0] + 1.f) * .5f;
    float u1 = (pts[3 * idx[k] + 1] + 1.f) * .5f;
    float u2 = (pts[3 * idx[k] + 2] + 1.f) * .5f;
    ua[k][0] = u0; ub[k][0] = u1;
    ua[k][1] = u0; ub[k][1] = u2;
    ua[k][2] = u1; ub[k][2] = u2;
  }
  const float sc[2] = {scA, scB};
  const unsigned st[2] = {stA, stB}, o[2] = {oA, oB};

  uint2 g[2][2][3][2];
  float rx[2][2][3], ry[2][2][3];
#pragma unroll
  for (int k = 0; k < 2; ++k)
#pragma unroll
    for (int l = 0; l < 2; ++l)
#pragma unroll
      for (int p = 0; p < 3; ++p) {
        float px = ua[k][p] * sc[l] + .5f, py = ub[k][p] * sc[l] + .5f;
        float fx = floorf(px), fy = floorf(py);
        rx[k][l][p] = px - fx; ry[k][l][p] = py - fy;
        unsigned i00 = (unsigned)fx + (unsigned)fy * st[l] + o[l];
        const unsigned* tp = tab + (size_t)p * total;
        g[k][l][p][0] = *reinterpret_cast<const uint2*>(tp + i00);
        g[k][l][p][1] = *reinterpret_cast<const uint2*>(tp + i00 + st[l]);
      }

#pragma unroll
  for (int k = 0; k < 2; ++k)
#pragma unroll
    for (int l = 0; l < 2; ++l) {
      float s0 = 0.f, s1 = 0.f;
#pragma unroll
      for (int p = 0; p < 3; ++p) {
        float x = rx[k][l][p], y = ry[k][l][p];
        float w00 = (1.f - x) * (1.f - y), w10 = x * (1.f - y);
        float w01 = (1.f - x) * y,          w11 = x * y;
        float2 f00 = h2f(g[k][l][p][0].x), f10 = h2f(g[k][l][p][0].y);
        float2 f01 = h2f(g[k][l][p][1].x), f11 = h2f(g[k][l][p][1].y);
        s0 += w00 * f00.x + w10 * f10.x + w01 * f01.x + w11 * f11.x;
        s1 += w00 * f00.y + w10 * f10.y + w01 * f01.y + w11 * f11.y;
      }
      unsigned hv = __builtin_bit_cast(unsigned, __floats2half2_rn(s0, s1));
      __builtin_nontemporal_store(hv, (l ? sB : sA) + idx[k]);
    }
}

// even-x0 trick: (x0+1)^hy == (x0^hy)^1 when x0 even -> aligned uint2 pair
__device__ __forceinline__ void hash_row(
    const unsigned* __restrict__ tp, unsigned x0, unsigned hy,
    unsigned& g0, unsigned& g1)
{
  unsigned a0 = (x0 ^ hy) & HMASK;
  if ((x0 & 1u) == 0u) {
    uint2 v = *reinterpret_cast<const uint2*>(tp + (a0 & ~1u));
    bool hi = (a0 & 1u) != 0u;
    g0 = hi ? v.y : v.x;
    g1 = hi ? v.x : v.y;
  } else {
    g0 = tp[a0];
    g1 = tp[((x0 + 1u) ^ hy) & HMASK];
  }
}

// ---- one hash level, all 3 planes, 2 pts/thread ----
__global__ __launch_bounds__(256) void k_hash_lvl(
    const float* __restrict__ pts, const unsigned* __restrict__ tab,
    unsigned* __restrict__ slice, float sc, unsigned o, unsigned total, int half)
{
  int t = blockIdx.x * 256 + threadIdx.x;
  if (t >= half) return;
  const int idx[2] = {t, t + half};

  float ua[2][3], ub[2][3];
#pragma unroll
  for (int k = 0; k < 2; ++k) {
    float u0 = (pts[3 * idx[k] + 0] + 1.f) * .5f;
    float u1 = (pts[3 * idx[k] + 1] + 1.f) * .5f;
    float u2 = (pts[3 * idx[k] + 2] + 1.f) * .5f;
    ua[k][0] = u0; ub[k][0] = u1;
    ua[k][1] = u0; ub[k][1] = u2;
    ua[k][2] = u1; ub[k][2] = u2;
  }

  unsigned g[2][3][4];
  float rx[2][3], ry[2][3];
#pragma unroll
  for (int k = 0; k < 2; ++k)
#pragma unroll
    for (int p = 0; p < 3; ++p) {
      float px = ua[k][p] * sc + .5f, py = ub[k][p] * sc + .5f;
      float fx = floorf(px), fy = floorf(py);
      rx[k][p] = px - fx; ry[k][p] = py - fy;
      unsigned x0 = (unsigned)fx, y0 = (unsigned)fy;
      unsigned hy0 = y0 * HASH_PRIME, hy1 = hy0 + HASH_PRIME;
      const unsigned* tp = tab + (size_t)p * total + o;
      hash_row(tp, x0, hy0, g[k][p][0], g[k][p][1]);
      hash_row(tp, x0, hy1, g[k][p][2], g[k][p][3]);
    }

#pragma unroll
  for (int k = 0; k < 2; ++k) {
    float s0 = 0.f, s1 = 0.f;
#pragma unroll
    for (int p = 0; p < 3; ++p) {
      float x = rx[k][p], y = ry[k][p];
      float w00 = (1.f - x) * (1.f - y), w10 = x * (1.f - y);
      float w01 = (1.f - x) * y,          w11 = x * y;
      float2 f00 = h2f(g[k][p][0]), f10 = h2f(g[k][p][1]);
      float2 f01 = h2f(g[k][p][2]), f11 = h2f(g[k][p][3]);
      s0 += w00 * f00.x + w10 * f10.x + w01 * f01.x + w11 * f11.x;
      s1 += w00 * f00.y + w10 * f10.y + w01 * f01.y + w11 * f11.y;
    }
    __builtin_nontemporal_store(
        __builtin_bit_cast(unsigned, __floats2half2_rn(s0, s1)), slice + idx[k]);
  }
}

// ---- final: persistent 512 blocks x 512 thr x 4 pts/thread.
//      LDS levels 0-5 staged once per block per plane (87MB total vs 348MB),
//      slices read late (short live range), plain full-line row stores. ----
__global__ __launch_bounds__(512) void k_final(
    const float* __restrict__ pts, const unsigned* __restrict__ tab,
    const unsigned* __restrict__ slices,   // 10 x n, levels 6..15
    float* __restrict__ out, LvlC lc, unsigned total, int n)
{
  __shared__ unsigned lds[LDS_WORDS];
  const int tid = threadIdx.x;
  const int base = blockIdx.x * 2048;      // 4 pts/thread

  int idx[2][2];
#pragma unroll
  for (int c = 0; c < 2; ++c)
#pragma unroll
    for (int k = 0; k < 2; ++k) idx[c][k] = base + c * 1024 + k * 512 + tid;

  float ua[2][2][3], ub[2][2][3];
#pragma unroll
  for (int c = 0; c < 2; ++c)
#pragma unroll
    for (int k = 0; k < 2; ++k) {
      float v0 = (pts[3 * idx[c][k] + 0] + 1.f) * .5f;
      float v1 = (pts[3 * idx[c][k] + 1] + 1.f) * .5f;
      float v2 = (pts[3 * idx[c][k] + 2] + 1.f) * .5f;
      ua[c][k][0] = v0; ub[c][k][0] = v1;
      ua[c][k][1] = v0; ub[c][k][1] = v2;
      ua[c][k][2] = v1; ub[c][k][2] = v2;
    }

  float res[2][2][12];
#pragma unroll
  for (int c = 0; c < 2; ++c)
#pragma unroll
    for (int k = 0; k < 2; ++k)
#pragma unroll
      for (int j = 0; j < 12; ++j) res[c][k][j] = 0.f;

  for (int p = 0; p < 3; ++p) {
    if (p) __syncthreads();
    const u4* src = reinterpret_cast<const u4*>(tab + (size_t)p * total);
    for (unsigned e = tid; e < LDS_WORDS / 4; e += 512)
      reinterpret_cast<u4*>(lds)[e] = src[e];
    __syncthreads();
#pragma unroll
    for (int l = 0; l < 6; ++l) {
      const float sc = lc.scale[l];
      const unsigned st = lc.stride[l], o = lc.offset[l];
#pragma unroll
      for (int c = 0; c < 2; ++c)
#pragma unroll
        for (int k = 0; k < 2; ++k) {
          float px = ua[c][k][p] * sc + .5f, py = ub[c][k][p] * sc + .5f;
          float fx = floorf(px), fy = floorf(py);
          float x = px - fx, y = py - fy;
          unsigned i00 = (unsigned)fx + (unsigned)fy * st + o;
          float2 f00 = h2f(lds[i00]),      f10 = h2f(lds[i00 + 1]);
          float2 f01 = h2f(lds[i00 + st]), f11 = h2f(lds[i00 + st + 1]);
          float w00 = (1.f - x) * (1.f - y), w10 = x * (1.f - y);
          float w01 = (1.f - x) * y,          w11 = x * y;
          res[c][k][2 * l + 0] += w00 * f00.x + w10 * f10.x + w01 * f01.x + w11 * f11.x;
          res[c][k][2 * l + 1] += w00 * f00.y + w10 * f10.y + w01 * f01.y + w11 * f11.y;
        }
    }
  }

#pragma unroll
  for (int c = 0; c < 2; ++c)
#pragma unroll
    for (int k = 0; k < 2; ++k) {
      unsigned sl[10];
#pragma unroll
      for (int j = 0; j < 10; ++j) sl[j] = slices[(size_t)j * n + idx[c][k]];
      float v[32];
#pragma unroll
      for (int j = 0; j < 12; ++j) v[j] = res[c][k][j];
#pragma unroll
      for (int j = 0; j < 10; ++j) {
        float2 f = h2f(sl[j]);
        v[12 + 2 * j] = f.x; v[12 + 2 * j + 1] = f.y;
      }
      float4* o4 = (float4*)(out + (size_t)idx[c][k] * 32);
#pragma unroll
      for (int j = 0; j < 8; ++j)
        o4[j] = make_float4(v[4 * j], v[4 * j + 1], v[4 * j + 2], v[4 * j + 3]);
    }
}

// ---- fallback: monolithic fp32 (guards failed) ----
__global__ __launch_bounds__(256) void k_fallback(
    const float* __restrict__ pts, const float2* __restrict__ txy,
    const float2* __restrict__ txz, const float2* __restrict__ tyz,
    float* __restrict__ out, LvlC lc, int n)
{
  int i = blockIdx.x * 256 + threadIdx.x;
  if (i >= n) return;
  float u0 = (pts[3 * i + 0] + 1.f) * .5f;
  float u1 = (pts[3 * i + 1] + 1.f) * .5f;
  float u2 = (pts[3 * i + 2] + 1.f) * .5f;
  const float ua[3] = {u0, u0, u1}, ub[3] = {u1, u2, u2};
  const float2* tabs[3] = {txy, txz, tyz};
  float acc[32];
#pragma unroll
  for (int j = 0; j < 32; ++j) acc[j] = 0.f;
#pragma unroll
  for (int l = 0; l < NLEV; ++l) {
    const float sc = lc.scale[l];
    const unsigned o = lc.offset[l], s = lc.stride[l];
#pragma unroll
    for (int p = 0; p < 3; ++p) {
      const float2* t = tabs[p];
      float px = ua[p] * sc + .5f, py = ub[p] * sc + .5f;
      float fx = floorf(px), fy = floorf(py);
      float rx = px - fx, ry = py - fy;
      unsigned x0 = (unsigned)fx, y0 = (unsigned)fy;
      float w00 = (1.f - rx) * (1.f - ry), w10 = rx * (1.f - ry);
      float w01 = (1.f - rx) * ry,          w11 = rx * ry;
      float2 f00, f10, f01, f11;
      if (l >= HASH_START) {
        unsigned hy0 = y0 * HASH_PRIME, hy1 = hy0 + HASH_PRIME;
        f00 = t[o + ((x0 ^ hy0) & HMASK)];
        f10 = t[o + (((x0 + 1u) ^ hy0) & HMASK)];
        f01 = t[o + ((x0 ^ hy1) & HMASK)];
        f11 = t[o + (((x0 + 1u) ^ hy1) & HMASK)];
      } else {
        unsigned i00 = x0 + y0 * s;
        float4 r0 = *reinterpret_cast<const float4*>(t + o + i00);
        float4 r1 = *reinterpret_cast<const float4*>(t + o + i00 + s);
        f00 = make_float2(r0.x, r0.y); f10 = make_float2(r0.z, r0.w);
        f01 = make_float2(r1.x, r1.y); f11 = make_float2(r1.z, r1.w);
      }
      acc[2 * l + 0] += w00 * f00.x + w10 * f10.x + w01 * f01.x + w11 * f11.x;
      acc[2 * l + 1] += w00 * f00.y + w10 * f10.y + w01 * f01.y + w11 * f11.y;
    }
  }
  float4* o4 = (float4*)(out + (size_t)i * 32);
#pragma unroll
  for (int j = 0; j < 8; ++j)
    o4[j] = make_float4(acc[4 * j], acc[4 * j + 1], acc[4 * j + 2], acc[4 * j + 3]);
}

static unsigned compute_levels(LvlC* lc)
{
  // Mirrors Python _level_constants() with identical double-precision ops.
  const double pls = std::pow(2.0, std::log2(2048.0 / 16.0) / 15.0);
  unsigned long long off = 0;
  for (int l = 0; l < NLEV; ++l) {
    double s = 16.0 * std::pow(pls, (double)l) - 1.0;
    lc->scale[l] = (float)s;
    long long r = (long long)std::ceil(s) + 1;
    long long dense = (r + 1) * (r + 1);
    long long sz = dense < (1LL << 19) ? dense : (1LL << 19);
    sz = ((sz + 7) / 8) * 8;
    lc->stride[l] = (unsigned)(r + 1);
    lc->offset[l] = (unsigned)off;
    off += (unsigned long long)sz;
  }
  return (unsigned)off;
}

extern "C" void kernel_launch(void* const* d_in, const int* in_sizes, int n_in,
                              void* d_out, int out_size, void* d_ws, size_t ws_size,
                              hipStream_t stream) {
  const float*  pts = (const float*)d_in[0];
  const float2* txy = (const float2*)d_in[1];
  const float2* txz = (const float2*)d_in[2];
  const float2* tyz = (const float2*)d_in[3];
  float* out = (float*)d_out;
  int n = in_sizes[0] / 3;  // 1048576 points

  LvlC lc;
  unsigned total = compute_levels(&lc);

  size_t tab_bytes = (size_t)3 * total * 4;
  size_t tab_al = (tab_bytes + 255) & ~(size_t)255;
  size_t need = tab_al + (size_t)10 * n * 4;

  bool ok = (n % 2048 == 0) && (lc.offset[6] == LDS_WORDS) && (ws_size >= need);
  for (int l = HASH_START; l < NLEV; ++l) {
    unsigned sz = ((l + 1 < NLEV) ? lc.offset[l + 1] : total) - lc.offset[l];
    ok = ok && (sz == (1u << 19));
  }

  int block = 256;
  int grid = (n + block - 1) / block;
  if (!ok) {
    k_fallback<<<grid, block, 0, stream>>>(pts, txy, txz, tyz, out, lc, n);
    return;
  }

  unsigned* tab16 = (unsigned*)d_ws;
  unsigned* slices = (unsigned*)((char*)d_ws + tab_al);  // 10 x n (levels 6..15)

  int half = n / 2;
  int gridh = half / block;

  k_convert<<<2048, 256, 0, stream>>>(txy, txz, tyz, tab16, total);
  for (int grp = 0; grp < 3; ++grp) {
    int lA = 6 + 2 * grp, lB = lA + 1;
    k_dense_pair<<<gridh, block, 0, stream>>>(
        pts, tab16,
        slices + (size_t)(lA - 6) * n, slices + (size_t)(lB - 6) * n,
        lc.scale[lA], lc.stride[lA], lc.offset[lA],
        lc.scale[lB], lc.stride[lB], lc.offset[lB], total, half);
  }
  for (int l = HASH_START; l < NLEV; ++l)
    k_hash_lvl<<<gridh, block, 0, stream>>>(pts, tab16, slices + (size_t)(l - 6) * n,
                                            lc.scale[l], lc.offset[l], total, half);
  k_final<<<n / 2048, 512, 0, stream>>>(pts, tab16, slices, out, lc, total, n);
}

// Round 15
// 321.088 us; speedup vs baseline: 1.4289x; 1.1128x over previous
//
#include <hip/hip_runtime.h>
#include <hip/hip_fp16.h>
#include <cmath>

#define NLEV 16
#define HASH_START 12               // levels >= 12 use spatial hash ((r+1)^2 > 2^19)
#define HMASK ((1u << 19) - 1u)     // hash level size is exactly 2^19
#define HASH_PRIME 2654435761u
#define LDS_WORDS 14160             // offset[6]: entries of levels 0-5 (host-guarded)

typedef float    f4 __attribute__((ext_vector_type(4)));
typedef unsigned u4 __attribute__((ext_vector_type(4)));

struct LvlC {
  float scale[NLEV];
  unsigned stride[NLEV];   // res + 1
  unsigned offset[NLEV];   // cumulative param offset (multiple of 8)
};

__device__ __forceinline__ float2 h2f(unsigned u) {
  return __half22float2(__builtin_bit_cast(__half2, u));
}

// ---- pass 0: fp32 tables -> fp16 copies in ws ----
__global__ __launch_bounds__(256) void k_convert(
    const float2* __restrict__ t0, const float2* __restrict__ t1,
    const float2* __restrict__ t2, unsigned* __restrict__ dst, unsigned total)
{
  unsigned g = blockIdx.x * 256 + threadIdx.x;
  unsigned stp = gridDim.x * 256;
  unsigned tot3 = 3u * total;
  for (unsigned e = g; e < tot3; e += stp) {
    const float2* src; unsigned i = e;
    if (i < total)            { src = t0; }
    else if (i < 2u * total)  { src = t1; i -= total; }
    else                      { src = t2; i -= 2u * total; }
    float2 v = src[i];
    __half2 h = __floats2half2_rn(v.x, v.y);
    __builtin_nontemporal_store(__builtin_bit_cast(unsigned, h), dst + e);
  }
}

// even-x0 trick: (x0+1)^hy == (x0^hy)^1 when x0 even -> aligned uint2 pair
__device__ __forceinline__ void hash_row(
    const unsigned* __restrict__ tp, unsigned x0, unsigned hy,
    unsigned& g0, unsigned& g1)
{
  unsigned a0 = (x0 ^ hy) & HMASK;
  if ((x0 & 1u) == 0u) {
    uint2 v = *reinterpret_cast<const uint2*>(tp + (a0 & ~1u));
    bool hi = (a0 & 1u) != 0u;
    g0 = hi ? v.y : v.x;
    g1 = hi ? v.x : v.y;
  } else {
    g0 = tp[a0];
    g1 = tp[((x0 + 1u) ^ hy) & HMASK];
  }
}

// ---- one hash level, all 3 planes, 2 pts/thread ----
__global__ __launch_bounds__(256) void k_hash_lvl(
    const float* __restrict__ pts, const unsigned* __restrict__ tab,
    unsigned* __restrict__ slice, float sc, unsigned o, unsigned total, int half)
{
  int t = blockIdx.x * 256 + threadIdx.x;
  if (t >= half) return;
  const int idx[2] = {t, t + half};

  float ua[2][3], ub[2][3];
#pragma unroll
  for (int k = 0; k < 2; ++k) {
    float u0 = (pts[3 * idx[k] + 0] + 1.f) * .5f;
    float u1 = (pts[3 * idx[k] + 1] + 1.f) * .5f;
    float u2 = (pts[3 * idx[k] + 2] + 1.f) * .5f;
    ua[k][0] = u0; ub[k][0] = u1;
    ua[k][1] = u0; ub[k][1] = u2;
    ua[k][2] = u1; ub[k][2] = u2;
  }

  unsigned g[2][3][4];
  float rx[2][3], ry[2][3];
#pragma unroll
  for (int k = 0; k < 2; ++k)
#pragma unroll
    for (int p = 0; p < 3; ++p) {
      float px = ua[k][p] * sc + .5f, py = ub[k][p] * sc + .5f;
      float fx = floorf(px), fy = floorf(py);
      rx[k][p] = px - fx; ry[k][p] = py - fy;
      unsigned x0 = (unsigned)fx, y0 = (unsigned)fy;
      unsigned hy0 = y0 * HASH_PRIME, hy1 = hy0 + HASH_PRIME;
      const unsigned* tp = tab + (size_t)p * total + o;
      hash_row(tp, x0, hy0, g[k][p][0], g[k][p][1]);
      hash_row(tp, x0, hy1, g[k][p][2], g[k][p][3]);
    }

#pragma unroll
  for (int k = 0; k < 2; ++k) {
    float s0 = 0.f, s1 = 0.f;
#pragma unroll
    for (int p = 0; p < 3; ++p) {
      float x = rx[k][p], y = ry[k][p];
      float w00 = (1.f - x) * (1.f - y), w10 = x * (1.f - y);
      float w01 = (1.f - x) * y,          w11 = x * y;
      float2 f00 = h2f(g[k][p][0]), f10 = h2f(g[k][p][1]);
      float2 f01 = h2f(g[k][p][2]), f11 = h2f(g[k][p][3]);
      s0 += w00 * f00.x + w10 * f10.x + w01 * f01.x + w11 * f11.x;
      s1 += w00 * f00.y + w10 * f10.y + w01 * f01.y + w11 * f11.y;
    }
    __builtin_nontemporal_store(
        __builtin_bit_cast(unsigned, __floats2half2_rn(s0, s1)), slice + idx[k]);
  }
}

// ---- final: per plane-phase p: {issue LDS staging + issue dense group p's
//      uint2 gathers} -> barrier (drains both) -> LDS levels 0-5 compute ->
//      consume dense group p. Dense latency hides under staging + LDS work.
//      Then 4 hash slices merged, one full-line row store. ----
__global__ __launch_bounds__(512) void k_final(
    const float* __restrict__ pts, const unsigned* __restrict__ tab,
    const unsigned* __restrict__ slices,   // 4 x n, levels 12..15
    float* __restrict__ out, LvlC lc, unsigned total, int n)
{
  __shared__ unsigned lds[LDS_WORDS];
  int i = blockIdx.x * 512 + threadIdx.x;   // n % 512 == 0 (host-guarded)

  float u0 = (pts[3 * i + 0] + 1.f) * .5f;
  float u1 = (pts[3 * i + 1] + 1.f) * .5f;
  float u2 = (pts[3 * i + 2] + 1.f) * .5f;
  const float ua[3] = {u0, u0, u1}, ub[3] = {u1, u2, u2};

  float res[24];                            // [0..12): levels 0-5; [12..24): levels 6-11
#pragma unroll
  for (int j = 0; j < 12; ++j) res[j] = 0.f;

  // dense group state (one 2-level group live at a time)
  uint2 g[2][3][2];
  float gx[2][3], gy[2][3];

#pragma unroll 1
  for (int p = 0; p < 3; ++p) {
    if (p) __syncthreads();
    // issue staging loads
    const u4* src = reinterpret_cast<const u4*>(tab + (size_t)p * total);
    for (unsigned e = threadIdx.x; e < LDS_WORDS / 4; e += 512)
      reinterpret_cast<u4*>(lds)[e] = src[e];
    // issue dense group p (levels 6+2p, 7+2p) -- grinds in TCP alongside staging
#pragma unroll
    for (int h = 0; h < 2; ++h) {
      const int l = 6 + 2 * p + h;
      const float sc = lc.scale[l];
      const unsigned st = lc.stride[l], o = lc.offset[l];
#pragma unroll
      for (int q = 0; q < 3; ++q) {
        float px = ua[q] * sc + .5f, py = ub[q] * sc + .5f;
        float fx = floorf(px), fy = floorf(py);
        gx[h][q] = px - fx; gy[h][q] = py - fy;
        unsigned i00 = (unsigned)fx + (unsigned)fy * st + o;
        const unsigned* tp = tab + (size_t)q * total;
        g[h][q][0] = *reinterpret_cast<const uint2*>(tp + i00);
        g[h][q][1] = *reinterpret_cast<const uint2*>(tp + i00 + st);
      }
    }
    __syncthreads();   // drains staging stores AND our dense loads together
    // LDS compute: levels 0-5, plane p
#pragma unroll
    for (int l = 0; l < 6; ++l) {
      const float sc = lc.scale[l];
      const unsigned st = lc.stride[l], o = lc.offset[l];
      float px = ua[p] * sc + .5f, py = ub[p] * sc + .5f;
      float fx = floorf(px), fy = floorf(py);
      float x = px - fx, y = py - fy;
      unsigned i00 = (unsigned)fx + (unsigned)fy * st + o;
      float2 f00 = h2f(lds[i00]),      f10 = h2f(lds[i00 + 1]);
      float2 f01 = h2f(lds[i00 + st]), f11 = h2f(lds[i00 + st + 1]);
      float w00 = (1.f - x) * (1.f - y), w10 = x * (1.f - y);
      float w01 = (1.f - x) * y,          w11 = x * y;
      res[2 * l + 0] += w00 * f00.x + w10 * f10.x + w01 * f01.x + w11 * f11.x;
      res[2 * l + 1] += w00 * f00.y + w10 * f10.y + w01 * f01.y + w11 * f11.y;
    }
    // consume dense group p
#pragma unroll
    for (int h = 0; h < 2; ++h) {
      float s0 = 0.f, s1 = 0.f;
#pragma unroll
      for (int q = 0; q < 3; ++q) {
        float x = gx[h][q], y = gy[h][q];
        float w00 = (1.f - x) * (1.f - y), w10 = x * (1.f - y);
        float w01 = (1.f - x) * y,          w11 = x * y;
        float2 f00 = h2f(g[h][q][0].x), f10 = h2f(g[h][q][0].y);
        float2 f01 = h2f(g[h][q][1].x), f11 = h2f(g[h][q][1].y);
        s0 += w00 * f00.x + w10 * f10.x + w01 * f01.x + w11 * f11.x;
        s1 += w00 * f00.y + w10 * f10.y + w01 * f01.y + w11 * f11.y;
      }
      res[12 + 4 * p + 2 * h + 0] = s0;
      res[12 + 4 * p + 2 * h + 1] = s1;
    }
  }

  // hash slices (levels 12-15) + assemble + full-line row store
  unsigned sl[4];
#pragma unroll
  for (int j = 0; j < 4; ++j) sl[j] = slices[(size_t)j * n + i];

  float v[32];
#pragma unroll
  for (int j = 0; j < 24; ++j) v[j] = res[j];
#pragma unroll
  for (int j = 0; j < 4; ++j) {
    float2 f = h2f(sl[j]);
    v[24 + 2 * j] = f.x; v[24 + 2 * j + 1] = f.y;
  }
  float4* o4 = (float4*)(out + (size_t)i * 32);
#pragma unroll
  for (int j = 0; j < 8; ++j)
    o4[j] = make_float4(v[4 * j], v[4 * j + 1], v[4 * j + 2], v[4 * j + 3]);
}

// ---- fallback: monolithic fp32 (guards failed) ----
__global__ __launch_bounds__(256) void k_fallback(
    const float* __restrict__ pts, const float2* __restrict__ txy,
    const float2* __restrict__ txz, const float2* __restrict__ tyz,
    float* __restrict__ out, LvlC lc, int n)
{
  int i = blockIdx.x * 256 + threadIdx.x;
  if (i >= n) return;
  float u0 = (pts[3 * i + 0] + 1.f) * .5f;
  float u1 = (pts[3 * i + 1] + 1.f) * .5f;
  float u2 = (pts[3 * i + 2] + 1.f) * .5f;
  const float ua[3] = {u0, u0, u1}, ub[3] = {u1, u2, u2};
  const float2* tabs[3] = {txy, txz, tyz};
  float acc[32];
#pragma unroll
  for (int j = 0; j < 32; ++j) acc[j] = 0.f;
#pragma unroll
  for (int l = 0; l < NLEV; ++l) {
    const float sc = lc.scale[l];
    const unsigned o = lc.offset[l], s = lc.stride[l];
#pragma unroll
    for (int p = 0; p < 3; ++p) {
      const float2* t = tabs[p];
      float px = ua[p] * sc + .5f, py = ub[p] * sc + .5f;
      float fx = floorf(px), fy = floorf(py);
      float rx = px - fx, ry = py - fy;
      unsigned x0 = (unsigned)fx, y0 = (unsigned)fy;
      float w00 = (1.f - rx) * (1.f - ry), w10 = rx * (1.f - ry);
      float w01 = (1.f - rx) * ry,          w11 = rx * ry;
      float2 f00, f10, f01, f11;
      if (l >= HASH_START) {
        unsigned hy0 = y0 * HASH_PRIME, hy1 = hy0 + HASH_PRIME;
        f00 = t[o + ((x0 ^ hy0) & HMASK)];
        f10 = t[o + (((x0 + 1u) ^ hy0) & HMASK)];
        f01 = t[o + ((x0 ^ hy1) & HMASK)];
        f11 = t[o + (((x0 + 1u) ^ hy1) & HMASK)];
      } else {
        unsigned i00 = x0 + y0 * s;
        float4 r0 = *reinterpret_cast<const float4*>(t + o + i00);
        float4 r1 = *reinterpret_cast<const float4*>(t + o + i00 + s);
        f00 = make_float2(r0.x, r0.y); f10 = make_float2(r0.z, r0.w);
        f01 = make_float2(r1.x, r1.y); f11 = make_float2(r1.z, r1.w);
      }
      acc[2 * l + 0] += w00 * f00.x + w10 * f10.x + w01 * f01.x + w11 * f11.x;
      acc[2 * l + 1] += w00 * f00.y + w10 * f10.y + w01 * f01.y + w11 * f11.y;
    }
  }
  float4* o4 = (float4*)(out + (size_t)i * 32);
#pragma unroll
  for (int j = 0; j < 8; ++j)
    o4[j] = make_float4(acc[4 * j], acc[4 * j + 1], acc[4 * j + 2], acc[4 * j + 3]);
}

static unsigned compute_levels(LvlC* lc)
{
  // Mirrors Python _level_constants() with identical double-precision ops.
  const double pls = std::pow(2.0, std::log2(2048.0 / 16.0) / 15.0);
  unsigned long long off = 0;
  for (int l = 0; l < NLEV; ++l) {
    double s = 16.0 * std::pow(pls, (double)l) - 1.0;
    lc->scale[l] = (float)s;
    long long r = (long long)std::ceil(s) + 1;
    long long dense = (r + 1) * (r + 1);
    long long sz = dense < (1LL << 19) ? dense : (1LL << 19);
    sz = ((sz + 7) / 8) * 8;
    lc->stride[l] = (unsigned)(r + 1);
    lc->offset[l] = (unsigned)off;
    off += (unsigned long long)sz;
  }
  return (unsigned)off;
}

extern "C" void kernel_launch(void* const* d_in, const int* in_sizes, int n_in,
                              void* d_out, int out_size, void* d_ws, size_t ws_size,
                              hipStream_t stream) {
  const float*  pts = (const float*)d_in[0];
  const float2* txy = (const float2*)d_in[1];
  const float2* txz = (const float2*)d_in[2];
  const float2* tyz = (const float2*)d_in[3];
  float* out = (float*)d_out;
  int n = in_sizes[0] / 3;  // 1048576 points

  LvlC lc;
  unsigned total = compute_levels(&lc);

  size_t tab_bytes = (size_t)3 * total * 4;
  size_t tab_al = (tab_bytes + 255) & ~(size_t)255;
  size_t need = tab_al + (size_t)4 * n * 4;

  bool ok = (n % 512 == 0) && (lc.offset[6] == LDS_WORDS) && (ws_size >= need);
  for (int l = HASH_START; l < NLEV; ++l) {
    unsigned sz = ((l + 1 < NLEV) ? lc.offset[l + 1] : total) - lc.offset[l];
    ok = ok && (sz == (1u << 19));
  }

  int block = 256;
  int grid = (n + block - 1) / block;
  if (!ok) {
    k_fallback<<<grid, block, 0, stream>>>(pts, txy, txz, tyz, out, lc, n);
    return;
  }

  unsigned* tab16 = (unsigned*)d_ws;
  unsigned* slices = (unsigned*)((char*)d_ws + tab_al);  // 4 x n (levels 12..15)

  int half = n / 2;
  int gridh = half / block;

  k_convert<<<2048, 256, 0, stream>>>(txy, txz, tyz, tab16, total);
  for (int l = HASH_START; l < NLEV; ++l)
    k_hash_lvl<<<gridh, block, 0, stream>>>(pts, tab16, slices + (size_t)(l - 12) * n,
                                            lc.scale[l], lc.offset[l], total, half);
  k_final<<<n / 512, 512, 0, stream>>>(pts, tab16, slices, out, lc, total, n);
}